// Round 4
// baseline (446.780 us; speedup 1.0000x reference)
//
#include <hip/hip_runtime.h>

constexpr int BATCH   = 16384;
constexpr int NCLS    = 1000;   // classes
constexpr int THREADS = 256;    // 4 waves
constexpr int BLOCKS  = 2048;   // 8192 waves -> 2 rows per wave

// Fused: one wave per row (grid-strided), per-block atomicAdd of partials,
// last block finalizes the mean. d_ws[0]=float accumulator, d_ws[1]=uint counter.
__global__ __launch_bounds__(THREADS)
void mpl_fused_kernel(const float* __restrict__ dist,
                      const int*   __restrict__ labels,
                      float*       __restrict__ acc,
                      unsigned*    __restrict__ cnt,
                      float*       __restrict__ out) {
    const int t    = threadIdx.x;
    const int lane = t & 63;
    const int wid  = t >> 6;
    const int gw   = blockIdx.x * 4 + wid;   // global wave id, 0..8191

    float partial = 0.0f;

    for (int row = gw; row < BATCH; row += BLOCKS * 4) {
        const float4* __restrict__ rp =
            reinterpret_cast<const float4*>(dist + (size_t)row * (NCLS * 4));
        const int lab = labels[row];

        float sum = 0.0f, incls = 0.0f;
        #pragma unroll
        for (int it = 0; it < 16; ++it) {
            const int c = it * 64 + lane;
            if (c < NCLS) {                       // iters 0..14 full, iter 15: lanes<40
                float4 v = rp[c];
                // soft-min over 4 prototypes: d = m - log(sum exp(m - x)), m = min
                float m = fminf(fminf(v.x, v.y), fminf(v.z, v.w));
                float s = __expf(m - v.x) + __expf(m - v.y) +
                          __expf(m - v.z) + __expf(m - v.w);
                float d = m - __logf(s);
                sum += d;
                if (c == lab) incls = d;          // exactly one lane across the wave
            }
        }
        // 64-lane butterfly reduction (incls: single nonzero lane -> sum works)
        #pragma unroll
        for (int off = 32; off; off >>= 1) {
            sum   += __shfl_xor(sum,   off, 64);
            incls += __shfl_xor(incls, off, 64);
        }
        if (lane == 0) {
            float om = (sum - incls) * (1.0f / (NCLS - 1));
            partial += (incls * incls) / (om * om);
        }
    }

    // combine the 4 waves' partials, one atomic per block
    __shared__ float s_p[4];
    if (lane == 0) s_p[wid] = partial;
    __syncthreads();
    if (t == 0) {
        float blk = (s_p[0] + s_p[1]) + (s_p[2] + s_p[3]);
        atomicAdd(acc, blk);
        __threadfence();                           // make the add visible device-wide
        unsigned done = atomicAdd(cnt, 1u);
        if (done == gridDim.x - 1) {
            // all blocks' acc-adds happen-before their cnt increments -> acc complete
            float total = atomicAdd(acc, 0.0f);    // coherent device-scope read
            out[0] = total * (1.0f / BATCH);
        }
    }
}

extern "C" void kernel_launch(void* const* d_in, const int* in_sizes, int n_in,
                              void* d_out, int out_size, void* d_ws, size_t ws_size,
                              hipStream_t stream) {
    const float* dist   = (const float*)d_in[0];
    const int*   labels = (const int*)d_in[1];
    float*       acc    = (float*)d_ws;
    unsigned*    cnt    = (unsigned*)d_ws + 1;
    float*       out    = (float*)d_out;

    hipMemsetAsync(d_ws, 0, 8, stream);            // zero acc + counter (capture-safe)
    mpl_fused_kernel<<<BLOCKS, THREADS, 0, stream>>>(dist, labels, acc, cnt, out);
}